// Round 2
// baseline (336.150 us; speedup 1.0000x reference)
//
#include <hip/hip_runtime.h>
#include <stdint.h>

#define IN1 16
#define HIDC 10
#define OUT3 16
#define NTYPES 25
#define MAXB 32
#define XSTR 16   // padded row stride (floats) for x/h buffers: 64B-aligned float4 loads

// ---------------- zero two int regions ----------------
__global__ __launch_bounds__(256) void zero2_kernel(int* __restrict__ a, int na,
                                                    int* __restrict__ b, int nb) {
  int i = blockIdx.x * blockDim.x + threadIdx.x;
  int s = gridDim.x * blockDim.x;
  for (int j = i; j < na; j += s) a[j] = 0;
  for (int j = i; j < nb; j += s) b[j] = 0;
}

// ---------------- histogram + within-bucket rank (1 atomic per edge) ----------
__global__ __launch_bounds__(256) void hist_kernel(const int* __restrict__ edst,
                                                   int* __restrict__ deg,
                                                   int* __restrict__ pos, int E) {
  int e = blockIdx.x * blockDim.x + threadIdx.x;
  if (e < E) pos[e] = atomicAdd(&deg[edst[e]], 1);
}

// ---------------- single-block exclusive scan (int4 vectorized) ----------------
__global__ __launch_bounds__(1024) void scan_kernel(const int4* __restrict__ deg4,
                                                    int* __restrict__ row_ptr, int N) {
  __shared__ int wsums[16];
  __shared__ int s_run;
  int tid = threadIdx.x, lane = tid & 63, wid = tid >> 6;
  if (tid == 0) s_run = 0;
  __syncthreads();
  int N4 = (N + 3) >> 2;
  for (int base = 0; base < N4; base += 1024) {
    int i4 = base + tid;
    int4 v = make_int4(0, 0, 0, 0);
    if (i4 < N4) v = deg4[i4];
    int idx0 = i4 * 4;
    if (idx0 + 1 >= N) v.y = 0;
    if (idx0 + 2 >= N) v.z = 0;
    if (idx0 + 3 >= N) v.w = 0;
    int s = v.x + v.y + v.z + v.w;
    int x = s;
    #pragma unroll
    for (int off = 1; off < 64; off <<= 1) {
      int y = __shfl_up(x, off);
      if (lane >= off) x += y;
    }
    if (lane == 63) wsums[wid] = x;
    __syncthreads();
    if (tid < 16) {
      int w = wsums[tid];
      #pragma unroll
      for (int off = 1; off < 16; off <<= 1) {
        int y = __shfl_up(w, off);
        if (tid >= off) w += y;
      }
      wsums[tid] = w;
    }
    __syncthreads();
    int excl = x - s + ((wid > 0) ? wsums[wid - 1] : 0) + s_run;
    int total = wsums[15];
    if (idx0 < N) row_ptr[idx0] = excl;
    if (idx0 + 1 < N) row_ptr[idx0 + 1] = excl + v.x;
    if (idx0 + 2 < N) row_ptr[idx0 + 2] = excl + v.x + v.y;
    if (idx0 + 3 < N) row_ptr[idx0 + 3] = excl + v.x + v.y + v.z;
    __syncthreads();
    if (tid == 0) s_run += total;
    __syncthreads();
  }
  if (threadIdx.x == 0) row_ptr[N] = s_run;
}

// ---------------- scatter edges into CSR order (plain stores) ----------------
__global__ __launch_bounds__(256) void permute_kernel(
    const int* __restrict__ edst, const int* __restrict__ esrc,
    const int* __restrict__ et, const float2* __restrict__ ef,
    const int* __restrict__ row_ptr, const int* __restrict__ pos,
    int4* __restrict__ edges, int E) {
  int e = blockIdx.x * blockDim.x + threadIdx.x;
  if (e >= E) return;
  int d = edst[e];
  int idx = row_ptr[d] + pos[e];
  float2 f = ef[e];
  int4 r;
  r.x = esrc[e];
  r.y = et[e];
  r.z = __float_as_int(f.x);
  r.w = __float_as_int(f.y);
  edges[idx] = r;
}

// ---------------- fused gather layer: msg-agg + mean + root + bias + relu -----
// Coefficients (wh/bh/wg/bg) live in per-lane REGISTERS (lane's output column
// oc is fixed -> it only needs k = i*O+oc). Only emb stays in LDS (runtime t).
// ISPLIT=2: 32 lanes/node, i-range split across two 16-lane halves, combined
// with one shfl_xor(16). ISPLIT=1: 16 lanes/node, full i-range in registers.
// A/B software pipeline: record prefetch depth 2, x-row loaded one step ahead.
template<int IN_C, int O, int ISPLIT, bool POOL, int BS>
__global__ __launch_bounds__(BS) void layer_kernel(
    const float* __restrict__ xin,      // [N, XSTR]
    const int4* __restrict__ edges,     // CSR by dst: {src, type, f0, f1}
    const int* __restrict__ row_ptr,    // [N+1]
    const float* __restrict__ emb,      // [25, D]
    const float* __restrict__ wh, const float* __restrict__ bh,
    const float* __restrict__ wg, const float* __restrict__ bg,
    const float* __restrict__ root,     // [IN_C, O]
    const float* __restrict__ bias,     // [O]
    float* __restrict__ hout,           // [N, XSTR], or psum[B*16] if POOL
    const int* __restrict__ ctype, const int* __restrict__ bids,
    float* __restrict__ pcnt,           // [B] (POOL only)
    int N, int B)
{
  constexpr int D = IN_C * O;
  constexpr int ESTR = D + 16;          // row pad: (ESTR%32)*4B staggers banks
  constexpr int G = 16 * ISPLIT;        // lanes per node
  constexpr int NPB = BS / G;           // nodes per block
  constexpr int IH = IN_C / ISPLIT;     // i's handled per lane
  __shared__ float s_emb[NTYPES * ESTR];
  __shared__ float s_root[D];
  __shared__ float s_bias[O];
  __shared__ float s_psum[POOL ? (MAXB * 16) : 1];
  __shared__ float s_pcnt[POOL ? MAXB : 1];

  int tid = threadIdx.x;
  for (int k = tid; k < NTYPES * D; k += BS) {
    int t = k / D, j = k - t * D;
    s_emb[t * ESTR + j] = emb[k];
  }
  for (int k = tid; k < D; k += BS) s_root[k] = root[k];
  if (tid < O) s_bias[tid] = bias[tid];
  if (POOL) {
    for (int i = tid; i < MAXB * 16; i += BS) s_psum[i] = 0.f;
    for (int i = tid; i < MAXB; i += BS) s_pcnt[i] = 0.f;
  }
  __syncthreads();

  int lg = tid & (G - 1);
  int o = lg & 15;
  int ihalf = lg >> 4;                  // 0..ISPLIT-1
  int nl = tid / G;
  int n = blockIdx.x * NPB + nl;
  int oc = (O == 16) ? o : ((o < O) ? o : 0);   // clamp idle lanes
  int i0 = ihalf * IH;
  int kbase = i0 * O + oc;

  // per-lane coefficient registers (static indexing only)
  float cwh0[IH], cwh1[IH], cbh[IH], cwg0[IH], cwg1[IH], cbg[IH];
  #pragma unroll
  for (int s = 0; s < IH; ++s) {
    int k = kbase + s * O;
    cwh0[s] = wh[k]; cwh1[s] = wh[D + k]; cbh[s] = bh[k];
    cwg0[s] = wg[k]; cwg1[s] = wg[D + k]; cbg[s] = bg[k];
  }

  float acc0 = 0.f, acc1 = 0.f;
  int start = 0, end = 0;
  if (n < N) { start = row_ptr[n]; end = row_ptr[n + 1]; }
  int nE = end - start;
  const int4* __restrict__ ep = edges + start;

  float xa[IH], xb[IH];
  int4 rA = make_int4(0, 0, 0, 0), rB = make_int4(0, 0, 0, 0);

  auto loadx = [&](float* xd, int src) {
    const float* __restrict__ p = xin + (size_t)src * XSTR + i0;
    if constexpr (IH == 8) {            // i0 in {0,8}: 16B aligned
      float4 v0 = ((const float4*)p)[0];
      float4 v1 = ((const float4*)p)[1];
      xd[0] = v0.x; xd[1] = v0.y; xd[2] = v0.z; xd[3] = v0.w;
      xd[4] = v1.x; xd[5] = v1.y; xd[6] = v1.z; xd[7] = v1.w;
    } else {                            // IH == 10, i0 == 0
      float4 v0 = ((const float4*)p)[0];
      float4 v1 = ((const float4*)p)[1];
      float2 v2 = ((const float2*)p)[4];
      xd[0] = v0.x; xd[1] = v0.y; xd[2] = v0.z; xd[3] = v0.w;
      xd[4] = v1.x; xd[5] = v1.y; xd[6] = v1.z; xd[7] = v1.w;
      xd[8] = v2.x; xd[9] = v2.y;
    }
  };
  auto edge_compute = [&](const int4& r, const float* xd) {
    int t = r.y;
    float f0 = __int_as_float(r.z), f1 = __int_as_float(r.w);
    const float* __restrict__ er = s_emb + t * ESTR + kbase;
    #pragma unroll
    for (int s = 0; s < IH; ++s) {
      float h = fmaf(f0, cwh0[s], fmaf(f1, cwh1[s], cbh[s]));
      float g = fmaf(f0, cwg0[s], fmaf(f1, cwg1[s], cbg[s]));
      float w = fmaxf(fmaf(er[s * O], h, g), 0.f);
      if (s & 1) acc1 = fmaf(xd[s], w, acc1);
      else       acc0 = fmaf(xd[s], w, acc0);
    }
  };

  if (nE > 0) {
    rA = ep[0];
    if (nE > 1) rB = ep[1];
    loadx(xa, rA.x);
    if (nE > 1) loadx(xb, rB.x);
    int j = 0;
    while (true) {
      { // A step: prefetch record j+2, compute edge j, refill x-row for j+2
        bool pf = (j + 2 < nE);
        int4 rn = make_int4(0, 0, 0, 0);
        if (pf) rn = ep[j + 2];
        edge_compute(rA, xa);
        if (pf) { rA = rn; loadx(xa, rA.x); }
      }
      if (++j >= nE) break;
      { // B step
        bool pf = (j + 2 < nE);
        int4 rn = make_int4(0, 0, 0, 0);
        if (pf) rn = ep[j + 2];
        edge_compute(rB, xb);
        if (pf) { rB = rn; loadx(xb, rB.x); }
      }
      if (++j >= nE) break;
    }
  }

  float acc = acc0 + acc1;
  if constexpr (ISPLIT == 2) acc += __shfl_xor(acc, 16);

  if (n < N && ihalf == 0 && o < O) {
    float inv = 1.0f / fmaxf((float)nE, 1.0f);
    float v = fmaf(acc, inv, s_bias[o]);
    const float* __restrict__ xr = xin + (size_t)n * XSTR;
    #pragma unroll
    for (int i = 0; i < IN_C; ++i) v = fmaf(xr[i], s_root[i * O + o], v);
    v = fmaxf(v, 0.f);
    if (!POOL) {
      hout[(size_t)n * XSTR + o] = v;
    } else {
      if (ctype[n] == 1) {
        int b = bids[n];
        atomicAdd(&s_psum[b * 16 + o], v);
        if (o == 0) atomicAdd(&s_pcnt[b], 1.0f);
      }
    }
  }

  if (POOL) {
    __syncthreads();
    for (int i = tid; i < B * 16; i += BS) {
      float v = s_psum[i];
      if (v != 0.f) atomicAdd(&hout[i], v);    // hout = psum (global)
    }
    for (int i = tid; i < B; i += BS) {
      float c = s_pcnt[i];
      if (c != 0.f) atomicAdd(&pcnt[i], c);
    }
  }
}

__global__ __launch_bounds__(256) void finalize_kernel(
    const float* __restrict__ psum, const float* __restrict__ pcnt,
    float* __restrict__ out, int B) {
  int i = blockIdx.x * blockDim.x + threadIdx.x;
  if (i >= B * OUT3) return;
  int b = i / OUT3;
  out[i] = psum[i] / fmaxf(pcnt[b], 1.0f);
}

// ---------------- launch ----------------
extern "C" void kernel_launch(void* const* d_in, const int* in_sizes, int n_in,
                              void* d_out, int out_size, void* d_ws, size_t ws_size,
                              hipStream_t stream)
{
  const float* x     = (const float*)d_in[0];
  const float* ef    = (const float*)d_in[1];
  const int*   et    = (const int*)d_in[2];
  const int*   esrc  = (const int*)d_in[3];
  const int*   edst  = (const int*)d_in[4];
  const int*   ctype = (const int*)d_in[5];
  const int*   bids  = (const int*)d_in[6];
  const float* emb1 = (const float*)d_in[8];
  const float* wh1  = (const float*)d_in[9];
  const float* bh1  = (const float*)d_in[10];
  const float* wg1  = (const float*)d_in[11];
  const float* bg1  = (const float*)d_in[12];
  const float* root1= (const float*)d_in[13];
  const float* bias1= (const float*)d_in[14];
  const float* emb2 = (const float*)d_in[15];
  const float* wh2  = (const float*)d_in[16];
  const float* bh2  = (const float*)d_in[17];
  const float* wg2  = (const float*)d_in[18];
  const float* bg2  = (const float*)d_in[19];
  const float* root2= (const float*)d_in[20];
  const float* bias2= (const float*)d_in[21];
  const float* emb3 = (const float*)d_in[22];
  const float* wh3  = (const float*)d_in[23];
  const float* bh3  = (const float*)d_in[24];
  const float* wg3  = (const float*)d_in[25];
  const float* bg3  = (const float*)d_in[26];
  const float* root3= (const float*)d_in[27];
  const float* bias3= (const float*)d_in[28];

  const int N = in_sizes[0] / IN1;
  const int E = in_sizes[2];
  const int B = out_size / OUT3;

  // workspace layout (16B-aligned sections)
  int4* edges   = (int4*)d_ws;                       // E recs (16B each)
  int*  deg     = (int*)(edges + E);                 // N
  int*  pos     = deg + N;                           // E
  int*  row_ptr = pos + E;                           // N+1
  float* h1 = (float*)((((uintptr_t)(row_ptr + (N + 1))) + 15) & ~(uintptr_t)15);
  float* h2     = h1 + (size_t)N * XSTR;             // N*XSTR
  float* psum   = h2 + (size_t)N * XSTR;             // B*16
  float* pcnt   = psum + (size_t)B * 16;             // B

  zero2_kernel<<<128, 256, 0, stream>>>(deg, N, (int*)psum, B * 16 + B);
  hist_kernel<<<(E + 255) / 256, 256, 0, stream>>>(edst, deg, pos, E);
  scan_kernel<<<1, 1024, 0, stream>>>((const int4*)deg, row_ptr, N);
  permute_kernel<<<(E + 255) / 256, 256, 0, stream>>>(
      edst, esrc, et, (const float2*)ef, row_ptr, pos, edges, E);

  // layer 1: IN_C=16 -> ISPLIT=2 (32 lanes/node, 48 coef regs/lane)
  const int g1 = (N + 7) / 8;          // 8 nodes per 256-thread block
  layer_kernel<IN1, HIDC, 2, false, 256><<<g1, 256, 0, stream>>>(
      x, edges, row_ptr, emb1, wh1, bh1, wg1, bg1, root1, bias1,
      h1, nullptr, nullptr, nullptr, N, B);
  // layer 2: IN_C=10 -> ISPLIT=1 (16 lanes/node, 60 coef regs/lane)
  const int g2 = (N + 15) / 16;
  layer_kernel<HIDC, HIDC, 1, false, 256><<<g2, 256, 0, stream>>>(
      h1, edges, row_ptr, emb2, wh2, bh2, wg2, bg2, root2, bias2,
      h2, nullptr, nullptr, nullptr, N, B);
  // layer 3 (+pool): IN_C=10 -> ISPLIT=1
  const int g3 = (N + 63) / 64;        // 64 nodes per 1024-thread block
  layer_kernel<HIDC, OUT3, 1, true, 1024><<<g3, 1024, 0, stream>>>(
      h2, edges, row_ptr, emb3, wh3, bh3, wg3, bg3, root3, bias3,
      psum, ctype, bids, pcnt, N, B);

  finalize_kernel<<<1, 256, 0, stream>>>(psum, pcnt, (float*)d_out, B);
}

// Round 3
// 257.921 us; speedup vs baseline: 1.3033x; 1.3033x over previous
//
#include <hip/hip_runtime.h>
#include <stdint.h>

#define IN1 16
#define HIDC 10
#define OUT3 16
#define NTYPES 25
#define MAXB 32

// ---------------- zero two int regions ----------------
__global__ __launch_bounds__(256) void zero2_kernel(int* __restrict__ a, int na,
                                                    int* __restrict__ b, int nb) {
  int i = blockIdx.x * blockDim.x + threadIdx.x;
  int s = gridDim.x * blockDim.x;
  for (int j = i; j < na; j += s) a[j] = 0;
  for (int j = i; j < nb; j += s) b[j] = 0;
}

// ---------------- histogram + within-bucket rank (1 atomic per edge) ----------
__global__ __launch_bounds__(256) void hist_kernel(const int* __restrict__ edst,
                                                   int* __restrict__ deg,
                                                   int* __restrict__ pos, int E) {
  int e = blockIdx.x * blockDim.x + threadIdx.x;
  if (e < E) pos[e] = atomicAdd(&deg[edst[e]], 1);
}

// ---------------- hierarchical scan: A) per-1024-chunk local scan + chunk sum
__global__ __launch_bounds__(256) void scan_part_kernel(const int* __restrict__ deg,
                                                        int* __restrict__ row_ptr,
                                                        int* __restrict__ bsum, int N) {
  __shared__ int wsums[4];
  int tid = threadIdx.x, lane = tid & 63, wid = tid >> 6;
  int idx0 = (blockIdx.x * 256 + tid) * 4;      // 4 scalar elements per thread
  int4 v = make_int4(0, 0, 0, 0);
  if (idx0 < N)     v.x = deg[idx0];
  if (idx0 + 1 < N) v.y = deg[idx0 + 1];
  if (idx0 + 2 < N) v.z = deg[idx0 + 2];
  if (idx0 + 3 < N) v.w = deg[idx0 + 3];
  int s = v.x + v.y + v.z + v.w;
  int x = s;
  #pragma unroll
  for (int off = 1; off < 64; off <<= 1) {
    int y = __shfl_up(x, off);
    if (lane >= off) x += y;
  }
  if (lane == 63) wsums[wid] = x;
  __syncthreads();
  int wpre = 0;
  #pragma unroll
  for (int w = 0; w < 4; ++w) if (w < wid) wpre += wsums[w];
  int excl = x - s + wpre;                      // block-local exclusive prefix
  if (idx0 < N)     row_ptr[idx0]     = excl;
  if (idx0 + 1 < N) row_ptr[idx0 + 1] = excl + v.x;
  if (idx0 + 2 < N) row_ptr[idx0 + 2] = excl + v.x + v.y;
  if (idx0 + 3 < N) row_ptr[idx0 + 3] = excl + v.x + v.y + v.z;
  if (tid == 255) bsum[blockIdx.x] = excl + s;  // chunk total
}

// B) single-wave exclusive scan of chunk sums (G <= 64); writes row_ptr[N]=E
__global__ __launch_bounds__(64) void scan_bsum_kernel(int* __restrict__ bsum,
                                                       int* __restrict__ row_ptr,
                                                       int G, int N) {
  int tid = threadIdx.x;
  int v = (tid < G) ? bsum[tid] : 0;
  int x = v;
  #pragma unroll
  for (int off = 1; off < 64; off <<= 1) {
    int y = __shfl_up(x, off);
    if (tid >= off) x += y;
  }
  if (tid < G) bsum[tid] = x - v;               // exclusive chunk offsets
  if (tid == 63) row_ptr[N] = x;                // grand total
}

// C) add chunk offset to each local prefix
__global__ __launch_bounds__(256) void scan_add_kernel(int* __restrict__ row_ptr,
                                                       const int* __restrict__ bsum,
                                                       int N) {
  int i = blockIdx.x * blockDim.x + threadIdx.x;
  if (i < N) row_ptr[i] += bsum[i >> 10];
}

// ---------------- scatter edges into CSR order (plain stores) ----------------
__global__ __launch_bounds__(256) void permute_kernel(
    const int* __restrict__ edst, const int* __restrict__ esrc,
    const int* __restrict__ et, const float2* __restrict__ ef,
    const int* __restrict__ row_ptr, const int* __restrict__ pos,
    int4* __restrict__ edges, int E) {
  int e = blockIdx.x * blockDim.x + threadIdx.x;
  if (e >= E) return;
  int d = edst[e];
  int idx = row_ptr[d] + pos[e];
  float2 f = ef[e];
  int4 r;
  r.x = esrc[e];
  r.y = et[e];
  r.z = __float_as_int(f.x);
  r.w = __float_as_int(f.y);
  edges[idx] = r;
}

// ---------------- fused gather layer: msg-agg + mean + root + bias + relu -----
// lane = (node_local, o16) with o16 in [0,16); 16 lanes per node.  (R0 structure)
template<int IN_C, int O, bool POOL, int BS>
__global__ __launch_bounds__(BS) void layer_kernel(
    const float* __restrict__ xin,      // [N, IN_C]
    const int4* __restrict__ edges,     // CSR by dst: {src, type, f0, f1}
    const int* __restrict__ row_ptr,    // [N+1]
    const float* __restrict__ emb,      // [25, D]
    const float* __restrict__ wh, const float* __restrict__ bh,
    const float* __restrict__ wg, const float* __restrict__ bg,
    const float* __restrict__ root,     // [IN_C, O]
    const float* __restrict__ bias,     // [O]
    float* __restrict__ hout,           // [N, O], or psum[B*16] if POOL
    const int* __restrict__ ctype, const int* __restrict__ bids,
    float* __restrict__ pcnt,           // [B] (POOL only)
    int N, int B)
{
  constexpr int D = IN_C * O;
  constexpr int ESTR = D + 8;           // padded LDS row stride for emb
  constexpr int NPB = BS / 16;          // nodes per block
  __shared__ float4 s_pa[D];            // {wh0,wh1,wg0,wg1}
  __shared__ float2 s_pb[D];            // {bh,bg}
  __shared__ float s_emb[NTYPES * ESTR];
  __shared__ float s_root[D];
  __shared__ float s_bias[O];
  __shared__ float s_psum[POOL ? (MAXB * 16) : 1];
  __shared__ float s_pcnt[POOL ? MAXB : 1];

  int tid = threadIdx.x;
  for (int k = tid; k < D; k += BS) {
    s_pa[k] = make_float4(wh[k], wh[D + k], wg[k], wg[D + k]);
    s_pb[k] = make_float2(bh[k], bg[k]);
    s_root[k] = root[k];
  }
  for (int k = tid; k < NTYPES * D; k += BS) {
    int t = k / D, j = k - t * D;
    s_emb[t * ESTR + j] = emb[k];
  }
  if (tid < O) s_bias[tid] = bias[tid];
  if (POOL) {
    for (int i = tid; i < MAXB * 16; i += BS) s_psum[i] = 0.f;
    for (int i = tid; i < MAXB; i += BS) s_pcnt[i] = 0.f;
  }
  __syncthreads();

  int nl = tid >> 4;
  int o = tid & 15;
  int oc = (O == 16) ? o : ((o < O) ? o : 0);   // clamp idle lanes
  int n = blockIdx.x * NPB + nl;

  float acc = 0.f;
  int start = 0, end = 0;
  if (n < N) { start = row_ptr[n]; end = row_ptr[n + 1]; }
  for (int e = start; e < end; ++e) {
    int4 r = edges[e];
    int src = r.x, t = r.y;
    float f0 = __int_as_float(r.z), f1 = __int_as_float(r.w);
    const float* __restrict__ xr = xin + (size_t)src * IN_C;
    const float* __restrict__ er = s_emb + t * ESTR;
    #pragma unroll
    for (int i = 0; i < IN_C; ++i) {
      int k = i * O + oc;
      float4 a = s_pa[k];
      float2 b = s_pb[k];
      float h = fmaf(f0, a.x, fmaf(f1, a.y, b.x));
      float g = fmaf(f0, a.z, fmaf(f1, a.w, b.y));
      float w = fmaxf(fmaf(er[k], h, g), 0.f);
      acc = fmaf(xr[i], w, acc);
    }
  }

  if (n < N && o < O) {
    float inv = 1.0f / fmaxf((float)(end - start), 1.0f);
    float v = fmaf(acc, inv, s_bias[o]);
    const float* __restrict__ xr = xin + (size_t)n * IN_C;
    #pragma unroll
    for (int i = 0; i < IN_C; ++i) v = fmaf(xr[i], s_root[i * O + o], v);
    v = fmaxf(v, 0.f);
    if (!POOL) {
      hout[(size_t)n * O + o] = v;
    } else {
      if (ctype[n] == 1) {
        int b = bids[n];
        atomicAdd(&s_psum[b * 16 + o], v);
        if (o == 0) atomicAdd(&s_pcnt[b], 1.0f);
      }
    }
  }

  if (POOL) {
    __syncthreads();
    for (int i = tid; i < B * 16; i += BS) {
      float v = s_psum[i];
      if (v != 0.f) atomicAdd(&hout[i], v);    // hout = psum (global)
    }
    for (int i = tid; i < B; i += BS) {
      float c = s_pcnt[i];
      if (c != 0.f) atomicAdd(&pcnt[i], c);
    }
  }
}

__global__ __launch_bounds__(256) void finalize_kernel(
    const float* __restrict__ psum, const float* __restrict__ pcnt,
    float* __restrict__ out, int B) {
  int i = blockIdx.x * blockDim.x + threadIdx.x;
  if (i >= B * OUT3) return;
  int b = i / OUT3;
  out[i] = psum[i] / fmaxf(pcnt[b], 1.0f);
}

// ---------------- launch ----------------
extern "C" void kernel_launch(void* const* d_in, const int* in_sizes, int n_in,
                              void* d_out, int out_size, void* d_ws, size_t ws_size,
                              hipStream_t stream)
{
  const float* x     = (const float*)d_in[0];
  const float* ef    = (const float*)d_in[1];
  const int*   et    = (const int*)d_in[2];
  const int*   esrc  = (const int*)d_in[3];
  const int*   edst  = (const int*)d_in[4];
  const int*   ctype = (const int*)d_in[5];
  const int*   bids  = (const int*)d_in[6];
  const float* emb1 = (const float*)d_in[8];
  const float* wh1  = (const float*)d_in[9];
  const float* bh1  = (const float*)d_in[10];
  const float* wg1  = (const float*)d_in[11];
  const float* bg1  = (const float*)d_in[12];
  const float* root1= (const float*)d_in[13];
  const float* bias1= (const float*)d_in[14];
  const float* emb2 = (const float*)d_in[15];
  const float* wh2  = (const float*)d_in[16];
  const float* bh2  = (const float*)d_in[17];
  const float* wg2  = (const float*)d_in[18];
  const float* bg2  = (const float*)d_in[19];
  const float* root2= (const float*)d_in[20];
  const float* bias2= (const float*)d_in[21];
  const float* emb3 = (const float*)d_in[22];
  const float* wh3  = (const float*)d_in[23];
  const float* bh3  = (const float*)d_in[24];
  const float* wg3  = (const float*)d_in[25];
  const float* bg3  = (const float*)d_in[26];
  const float* root3= (const float*)d_in[27];
  const float* bias3= (const float*)d_in[28];

  const int N = in_sizes[0] / IN1;
  const int E = in_sizes[2];
  const int B = out_size / OUT3;

  // workspace layout (16B-aligned sections)
  int4* edges   = (int4*)d_ws;                       // E recs (16B each)
  int*  deg     = (int*)(edges + E);                 // N
  int*  pos     = deg + N;                           // E
  int*  row_ptr = pos + E;                           // N+1
  int*  bsum    = row_ptr + (N + 1);                 // <=64 chunk sums
  float* h1     = (float*)(bsum + 64);               // N*HIDC
  float* h2     = h1 + (size_t)N * HIDC;             // N*HIDC
  float* psum   = h2 + (size_t)N * HIDC;             // B*16
  float* pcnt   = psum + (size_t)B * 16;             // B

  const int nChunk = (N + 1023) / 1024;              // 1024 deg entries per chunk

  zero2_kernel<<<128, 256, 0, stream>>>(deg, N, (int*)psum, B * 16 + B);
  hist_kernel<<<(E + 255) / 256, 256, 0, stream>>>(edst, deg, pos, E);
  scan_part_kernel<<<nChunk, 256, 0, stream>>>(deg, row_ptr, bsum, N);
  scan_bsum_kernel<<<1, 64, 0, stream>>>(bsum, row_ptr, nChunk, N);
  scan_add_kernel<<<(N + 255) / 256, 256, 0, stream>>>(row_ptr, bsum, N);
  permute_kernel<<<(E + 255) / 256, 256, 0, stream>>>(
      edst, esrc, et, (const float2*)ef, row_ptr, pos, edges, E);

  const int g256 = (N + 15) / 16;     // 16 nodes per 256-thread block
  layer_kernel<IN1, HIDC, false, 256><<<g256, 256, 0, stream>>>(
      x, edges, row_ptr, emb1, wh1, bh1, wg1, bg1, root1, bias1,
      h1, nullptr, nullptr, nullptr, N, B);
  layer_kernel<HIDC, HIDC, false, 256><<<g256, 256, 0, stream>>>(
      h1, edges, row_ptr, emb2, wh2, bh2, wg2, bg2, root2, bias2,
      h2, nullptr, nullptr, nullptr, N, B);

  const int g1024 = (N + 63) / 64;    // 64 nodes per 1024-thread block
  layer_kernel<HIDC, OUT3, true, 1024><<<g1024, 1024, 0, stream>>>(
      h2, edges, row_ptr, emb3, wh3, bh3, wg3, bg3, root3, bias3,
      psum, ctype, bids, pcnt, N, B);

  finalize_kernel<<<1, 256, 0, stream>>>(psum, pcnt, (float*)d_out, B);
}